// Round 1
// baseline (399.878 us; speedup 1.0000x reference)
//
#include <hip/hip_runtime.h>

#define KSZ 5
#define H 512
#define W 512
#define B 16
#define NCH 24  // KSZ*KSZ - 1

// One thread handles 4 consecutive x pixels for all 24 output channels.
// out[b,k,y,x] = x[b,y,x] - x[b, clamp(y+i-2,0,H-1), clamp(x+j-2,0,W-1)]
// k enumerates (i,j) in row-major order over the 5x5 window, skipping (2,2).
__global__ __launch_bounds__(256) void lv_kernel(const float* __restrict__ xin,
                                                 float* __restrict__ out) {
    int id = blockIdx.x * blockDim.x + threadIdx.x;  // 0 .. 16*512*128-1
    int x4 = id & 127;          // 128 groups of 4 px per row
    int y  = (id >> 7) & 511;
    int b  = id >> 16;
    int x0 = x4 << 2;

    const float* xb = xin + (size_t)b * (H * W);

    // clamped column indices for x0-2 .. x0+5
    int cols[8];
#pragma unroll
    for (int j = 0; j < 8; ++j) {
        int c = x0 - 2 + j;
        cols[j] = min(max(c, 0), W - 1);
    }

    // load 5 rows x 8 cols neighborhood (all cached: input is 16.8 MB total)
    float v[5][8];
#pragma unroll
    for (int i = 0; i < 5; ++i) {
        int r = min(max(y - 2 + i, 0), H - 1);
        const float* rp = xb + r * W;
#pragma unroll
        for (int j = 0; j < 8; ++j) v[i][j] = rp[cols[j]];
    }

    // center pixels for the 4 outputs: columns x0 .. x0+3 -> v[2][2..5]
    float c0 = v[2][2], c1 = v[2][3], c2 = v[2][4], c3 = v[2][5];

    float* ob = out + (size_t)b * NCH * H * W + (size_t)y * W + x0;
    int k = 0;
#pragma unroll
    for (int i = 0; i < 5; ++i) {
#pragma unroll
        for (int j = 0; j < 5; ++j) {
            if (i == 2 && j == 2) continue;
            float4 o;
            o.x = c0 - v[i][j + 0];
            o.y = c1 - v[i][j + 1];
            o.z = c2 - v[i][j + 2];
            o.w = c3 - v[i][j + 3];
            *(float4*)(ob + (size_t)k * (H * W)) = o;
            ++k;
        }
    }
}

extern "C" void kernel_launch(void* const* d_in, const int* in_sizes, int n_in,
                              void* d_out, int out_size, void* d_ws, size_t ws_size,
                              hipStream_t stream) {
    const float* x = (const float*)d_in[0];
    float* out = (float*)d_out;
    // total threads = B * H * (W/4) = 16*512*128 = 1,048,576
    int threads = 256;
    int blocks = (B * H * (W / 4)) / threads;  // 4096
    lv_kernel<<<blocks, threads, 0, stream>>>(x, out);
}